// Round 10
// baseline (186.858 us; speedup 1.0000x reference)
//
#include <hip/hip_runtime.h>
#include <stdint.h>

typedef __bf16 bf16x8 __attribute__((ext_vector_type(8)));
typedef float  f32x4  __attribute__((ext_vector_type(4)));
typedef unsigned int u32x4 __attribute__((ext_vector_type(4)));

#define S_   2048
#define DM   1024
// 0.125 (=1/sqrt(64)) * log2(e), folded into Q projection epilogue so the
// attention softmax is a bare exp2 with no per-element scaling.
#define QSCALE 0.18033688011112042f

__device__ __forceinline__ unsigned short f2b(float f) {
    uint32_t u = __builtin_bit_cast(uint32_t, f);
    u += 0x7fffu + ((u >> 16) & 1u);
    return (unsigned short)(u >> 16);
}

// round-half-up bf16 pair pack: 2 adds + 1 v_perm
__device__ __forceinline__ uint32_t pack2bf(float a, float b) {
    uint32_t ua = __builtin_bit_cast(uint32_t, a) + 0x8000u;
    uint32_t ub = __builtin_bit_cast(uint32_t, b) + 0x8000u;
    return __builtin_amdgcn_perm(ub, ua, 0x07060302);
}

__device__ __forceinline__ void glds16(const void* g, void* l) {
    __builtin_amdgcn_global_load_lds(
        (const __attribute__((address_space(1))) void*)g,
        (__attribute__((address_space(3))) void*)l, 16, 0, 0);
}

// ---------------------------------------------------------------------------
// fp32 -> bf16 for X (4M elems -> Xb in ws) and Wq/Wk/Wv (3x1M -> Wb in d_out
// scratch; consumed by qkv_gemm, which finishes before out_gemm writes d_out).
// ---------------------------------------------------------------------------
__global__ void cvt_all(const float* __restrict__ X,
                        const float* __restrict__ Wq, const float* __restrict__ Wk,
                        const float* __restrict__ Wv,
                        unsigned short* __restrict__ Xb, unsigned short* __restrict__ Wb)
{
    size_t i = ((size_t)blockIdx.x * 256 + threadIdx.x) * 4;
    const float* src;
    unsigned short* dst;
    size_t off;
    if (i < (size_t)4194304) { src = X; dst = Xb; off = i; }
    else {
        size_t j = i - 4194304;
        int sel = (int)(j >> 20);
        off = j & 1048575;
        src = (sel == 0) ? Wq : (sel == 1) ? Wk : Wv;
        dst = Wb + (size_t)sel * 1048576;
    }
    float4 v = *(const float4*)&src[off];
    uint2 o;
    o.x = pack2bf(v.x, v.y);
    o.y = pack2bf(v.z, v.w);
    *(uint2*)&dst[off] = o;
}

// ---------------------------------------------------------------------------
// Fused QKV projection, m97 structure: both operands bf16 via global_load_lds.
// z=0: Q[tok][feat] (scaled by QSCALE), z=1: K[tok][feat], z=2: Vt[feat][tok].
// Grid (32,8,3); the 32-range (token panels for z!=2) rides blockIdx.x, so
// XCD = x&7 and same-XCD blocks share the X row-panel in that XCD's L2.
// ---------------------------------------------------------------------------
__global__ __launch_bounds__(256, 2)
void qkv_gemm(const unsigned short* __restrict__ Xb,
              const unsigned short* __restrict__ Wqb,
              const unsigned short* __restrict__ Wkb,
              const unsigned short* __restrict__ Wvb,
              unsigned short* __restrict__ Qo, unsigned short* __restrict__ Ko,
              unsigned short* __restrict__ Vto)
{
    __shared__ unsigned short Ash[128 * 32];
    __shared__ unsigned short Bsh[128 * 32];

    const int t = threadIdx.x;
    const int lane = t & 63, w = t >> 6;
    const int lcol = lane & 15, quad = lane >> 4;
    const int z = blockIdx.z;
    // x spans 32 (token panels), y spans 8 (feature panels); roles swap at z=2
    const int rowBase = ((z == 2) ? blockIdx.y : blockIdx.x) * 128;
    const int colBase = ((z == 2) ? blockIdx.x : blockIdx.y) * 128;
    const unsigned short* aPtr = (z == 2) ? Wvb : Xb;
    const unsigned short* bPtr = (z == 0) ? Wqb : (z == 1) ? Wkb : Xb;
    const int wr = (w >> 1) * 64, wc = (w & 1) * 64;

    f32x4 acc[4][4];
    #pragma unroll
    for (int i = 0; i < 4; ++i)
        #pragma unroll
        for (int j = 0; j < 4; ++j) acc[i][j] = (f32x4){0.f,0.f,0.f,0.f};

    for (int k0 = 0; k0 < DM; k0 += 32) {
        __syncthreads();
        #pragma unroll
        for (int p = 0; p < 2; ++p) {
            int ci = p * 256 + t;
            glds16(&aPtr[(size_t)(rowBase + (ci >> 2)) * DM + k0 + (ci & 3) * 8], &Ash[ci * 8]);
        }
        #pragma unroll
        for (int p = 0; p < 2; ++p) {
            int ci = p * 256 + t;
            glds16(&bPtr[(size_t)(colBase + (ci >> 2)) * DM + k0 + (ci & 3) * 8], &Bsh[ci * 8]);
        }
        __syncthreads();
        bf16x8 af[4], bfr[4];
        #pragma unroll
        for (int i = 0; i < 4; ++i) af[i]  = *(const bf16x8*)&Ash[(wr + i*16 + lcol)*32 + quad*8];
        #pragma unroll
        for (int i = 0; i < 4; ++i) bfr[i] = *(const bf16x8*)&Bsh[(wc + i*16 + lcol)*32 + quad*8];
        #pragma unroll
        for (int i = 0; i < 4; ++i)
            #pragma unroll
            for (int j = 0; j < 4; ++j)
                acc[i][j] = __builtin_amdgcn_mfma_f32_16x16x32_bf16(af[i], bfr[j], acc[i][j], 0, 0, 0);
    }

    unsigned short* Cm = (z == 0) ? Qo : (z == 1) ? Ko : Vto;
    const int ld = (z == 2) ? (S_ * 2) : DM;
    const float sc = (z == 0) ? QSCALE : 1.0f;
    #pragma unroll
    for (int i = 0; i < 4; ++i)
        #pragma unroll
        for (int j = 0; j < 4; ++j)
            #pragma unroll
            for (int r = 0; r < 4; ++r) {
                int row = rowBase + wr + i*16 + quad*4 + r;
                int col = colBase + wc + j*16 + lcol;
                Cm[(size_t)row * ld + col] = f2b(acc[i][j][r] * sc);
            }
}

// ---------------------------------------------------------------------------
// Flash attention, causal, S^T form, fixed softmax shift. 512 thr / 8 waves.
// Exact R2-measured kernel (43.6-45.0 us). Model (validated R2/R3/R6): time =
// (chunk-instances per CU = 34) x ~3.2k cyc, distribution-invariant.
//   * waves = 4 q-groups(32 rows) x 2 k-halves(32): each K/V ds_read_b128
//     fragment feeds TWO 16-q MFMAs. One-time cross-wave o/l reduction at end.
//   * Ps LDS roundtrip eliminated: P -> PV-A-fragment via __shfl_xor(16) +
//     select; k-slot permutation sigma=[0,2,1,3] folded into V read offset.
// Causal bounds wave-uniform: k16 idx Kb = c*4 + kh*2 + nk, q16 idx
// Qb = tile*8 + wq*2 + qi, live iff Kb <= Qb, diagonal masked via mk[].
// Grid (32,16): bh = blockIdx.x pins bh to XCD; y<8 ? 15-y : y-8 keeps the
// complementary tile pairing.
// ---------------------------------------------------------------------------
__global__ __launch_bounds__(512, 4)
void attn_kernel(const unsigned short* __restrict__ Q,
                 const unsigned short* __restrict__ K,
                 const unsigned short* __restrict__ Vt,
                 unsigned short* __restrict__ Z)
{
    // [Kbuf0 | Kbuf1 | Vbuf0 | Vbuf1], each 64 rows x 72 shorts (16B row pad).
    // After the main loop the same 36,864B are reused as the f32 reduction
    // buffer (4 q-groups x 64 lanes x 36 f32, stride 144B -> 16B aligned).
    __shared__ __align__(16) unsigned short SH[18432];

    const int t = threadIdx.x;
    const int lane = t & 63, w = t >> 6;          // 8 waves
    const int lcol = lane & 15, quad = lane >> 4;
    const int kh = w & 1, wq = w >> 1;            // k-half (32), q-group (32)

    const int bh = blockIdx.x;                    // XCD = bh & 7
    const int b = bh >> 4, h = bh & 15;
    const int y = blockIdx.y;
    const int tile = (y < 8) ? (15 - y) : (y - 8);
    const int q0 = tile * 128;
    const int nchunk = 2 * tile + 2;              // k-chunks of 64

    const unsigned short* Qg = Q + (size_t)(b * S_ + q0) * DM + h * 64;
    const unsigned short* Kg = K + (size_t)(b * S_) * DM + h * 64;
    const unsigned short* Vg = Vt + (size_t)(h * 64) * (S_ * 2) + b * S_;

    // Q fragments: 2 q-subgroups of 16 x 2 hd-halves
    bf16x8 qf[2][2];
    #pragma unroll
    for (int qi = 0; qi < 2; ++qi)
        #pragma unroll
        for (int kd = 0; kd < 2; ++kd)
            qf[qi][kd] = *(const bf16x8*)&Qg[(size_t)(wq*32 + qi*16 + lcol) * DM + kd*32 + quad*8];

    // mask pattern inside the diagonal 16x16 block (S^T form: mask k > q)
    bool mk[4];
    #pragma unroll
    for (int r = 0; r < 4; ++r) mk[r] = (quad*4 + r) > lcol;

    float lp[2] = {0.f, 0.f};
    f32x4 o[2][4];
    #pragma unroll
    for (int qi = 0; qi < 2; ++qi)
        #pragma unroll
        for (int nd = 0; nd < 4; ++nd) o[qi][nd] = (f32x4){0.f,0.f,0.f,0.f};

    // staging: 64 rows x 8 16B-chunks per tile; one K + one V load per thread
    const int sr = t >> 3, sch = t & 7;

    // prologue: stage chunk 0 into buffer 0
    {
        uint4 k0 = *(const uint4*)&Kg[(size_t)sr * DM + sch * 8];
        uint4 v0 = *(const uint4*)&Vg[(size_t)sr * (S_ * 2) + sch * 8];
        *(uint4*)&SH[sr * 72 + sch * 8] = k0;
        *(uint4*)&SH[9216 + sr * 72 + sch * 8] = v0;
    }
    __syncthreads();

    const int Qb0 = tile * 8 + wq * 2;                  // q16 idx of qi=0
    const int gq = ((quad & 1) << 1) | (quad >> 1);     // sigma = [0,2,1,3]
    const bool qodd = (quad & 1) != 0;

    for (int c = 0; c < nchunk; ++c) {
        const int cur = c & 1;
        const bool pf = (c + 1 < nchunk);
        uint4 kn, vn;
        if (pf) {                                 // issue loads for chunk c+1
            const int kc1 = (c + 1) * 64;
            kn = *(const uint4*)&Kg[(size_t)(kc1 + sr) * DM + sch * 8];
            vn = *(const uint4*)&Vg[(size_t)sr * (S_ * 2) + kc1 + sch * 8];
        }
        const unsigned short* Kc = &SH[cur * 4608];
        const unsigned short* Vc = &SH[9216 + cur * 4608];

        const int Kb0 = c * 4 + kh * 2;           // k16 idx of nk=0
        if (Kb0 <= Qb0 + 1) {                     // at least (nk=0,qi=1) live
            uint32_t pw[2][2][2];                 // [qi][nk][word], bf16 pairs
            #pragma unroll
            for (int nk = 0; nk < 2; ++nk) {
                const int Kb = Kb0 + nk;
                if (Kb <= Qb0 + 1) {
                    bf16x8 ak0 = *(const bf16x8*)&Kc[(kh*32 + nk*16 + lcol)*72 + quad*8];
                    bf16x8 ak1 = *(const bf16x8*)&Kc[(kh*32 + nk*16 + lcol)*72 + 32 + quad*8];
                    #pragma unroll
                    for (int qi = 0; qi < 2; ++qi) {
                        if (Kb <= Qb0 + qi) {
                            f32x4 s = (f32x4){0.f,0.f,0.f,0.f};
                            s = __builtin_amdgcn_mfma_f32_16x16x32_bf16(ak0, qf[qi][0], s, 0, 0, 0);
                            s = __builtin_amdgcn_mfma_f32_16x16x32_bf16(ak1, qf[qi][1], s, 0, 0, 0);
                            float p0 = __builtin_amdgcn_exp2f(s[0]);
                            float p1 = __builtin_amdgcn_exp2f(s[1]);
                            float p2 = __builtin_amdgcn_exp2f(s[2]);
                            float p3 = __builtin_amdgcn_exp2f(s[3]);
                            if (Kb == Qb0 + qi) { // diagonal block, uniform
                                p0 = mk[0] ? 0.f : p0;
                                p1 = mk[1] ? 0.f : p1;
                                p2 = mk[2] ? 0.f : p2;
                                p3 = mk[3] ? 0.f : p3;
                            }
                            lp[qi] += (p0 + p1) + (p2 + p3);
                            pw[qi][nk][0] = pack2bf(p0, p1);
                            pw[qi][nk][1] = pack2bf(p2, p3);
                        } else {
                            pw[qi][nk][0] = 0u;
                            pw[qi][nk][1] = 0u;
                        }
                    }
                } else {
                    #pragma unroll
                    for (int qi = 0; qi < 2; ++qi) {
                        pw[qi][nk][0] = 0u;
                        pw[qi][nk][1] = 0u;
                    }
                }
            }

            // register->A-fragment transform via shfl_xor(16) + select.
            // Source: lane (quad,q) word layout  a0={4q,4q+1} a1={4q+2,4q+3}
            //         b0={16+4q,16+4q+1} b1={16+4q+2,16+4q+3}
            // Dest quad d holds k-group sigma(d)*8..+7 ascending, sigma=[0,2,1,3];
            // V reads apply the same sigma via gq.
            bf16x8 ap[2];
            #pragma unroll
            for (int qi = 0; qi < 2; ++qi) {
                uint32_t a0 = pw[qi][0][0], a1 = pw[qi][0][1];
                uint32_t b0 = pw[qi][1][0], b1 = pw[qi][1][1];
                uint32_t xa0 = (uint32_t)__shfl_xor((int)a0, 16);
                uint32_t xa1 = (uint32_t)__shfl_xor((int)a1, 16);
                uint32_t xb0 = (uint32_t)__shfl_xor((int)b0, 16);
                uint32_t xb1 = (uint32_t)__shfl_xor((int)b1, 16);
                u32x4 apw;
                apw[0] = qodd ? xb0 : a0;
                apw[1] = qodd ? xb1 : a1;
                apw[2] = qodd ? b0 : xa0;
                apw[3] = qodd ? b1 : xa1;
                ap[qi] = __builtin_bit_cast(bf16x8, apw);
            }

            #pragma unroll
            for (int nd = 0; nd < 4; ++nd) {
                bf16x8 bv = *(const bf16x8*)&Vc[(nd*16 + lcol)*72 + kh*32 + gq*8];
                #pragma unroll
                for (int qi = 0; qi < 2; ++qi)
                    o[qi][nd] = __builtin_amdgcn_mfma_f32_16x16x32_bf16(ap[qi], bv, o[qi][nd], 0, 0, 0);
            }
        }

        if (pf) {                                 // write chunk c+1 into buf^1
            *(uint4*)&SH[(cur ^ 1) * 4608 + sr * 72 + sch * 8] = kn;
            *(uint4*)&SH[9216 + (cur ^ 1) * 4608 + sr * 72 + sch * 8] = vn;
        }
        __syncthreads();   // readers of buf^1 (iter c-1) done before its write
                           // is visible-required; writers done before iter c+1
    }

    // ---- combine k-halves: partner waves (wq,kh=1) -> (wq,kh=0) via LDS ----
    #pragma unroll
    for (int qi = 0; qi < 2; ++qi) {
        lp[qi] += __shfl_xor(lp[qi], 16);
        lp[qi] += __shfl_xor(lp[qi], 32);
    }
    float* red = (float*)SH;
    float* my = red + (wq * 64 + lane) * 36;      // 144B stride: 16B aligned
    if (kh == 1) {
        #pragma unroll
        for (int qi = 0; qi < 2; ++qi)
            #pragma unroll
            for (int nd = 0; nd < 4; ++nd)
                *(f32x4*)&my[qi*16 + nd*4] = o[qi][nd];
        my[32] = lp[0];
        my[33] = lp[1];
    }
    __syncthreads();
    if (kh == 0) {
        #pragma unroll
        for (int qi = 0; qi < 2; ++qi)
            #pragma unroll
            for (int nd = 0; nd < 4; ++nd)
                o[qi][nd] += *(const f32x4*)&my[qi*16 + nd*4];
        float linv[2];
        linv[0] = 1.0f / (lp[0] + my[32]);
        linv[1] = 1.0f / (lp[1] + my[33]);
        #pragma unroll
        for (int qi = 0; qi < 2; ++qi)
            #pragma unroll
            for (int r = 0; r < 4; ++r) {
                float lr = __shfl(linv[qi], quad*4 + r);
                unsigned short* Zr = Z + (size_t)(b*S_ + q0 + wq*32 + qi*16 + quad*4 + r) * DM + h*64;
                #pragma unroll
                for (int nd = 0; nd < 4; ++nd)
                    Zr[nd*16 + lcol] = f2b(o[qi][nd][r] * lr);
            }
    }
}

// ---------------------------------------------------------------------------
// Output projection, R16: tile 128x128, grid (32,8), 256 thr / 4 waves.
// A (Zb, bf16) via glds16; B = Wo fp32 read DIRECTLY with in-staging bf16
// conversion (fuses the old cvt_wo kernel away): 512 16B-chunks per k-step,
// thread->chunk mapping == the glds16 lane pattern (consecutive lanes ->
// consecutive 16B -> coalesced reads, conflict-free ds_write_b128).
// pack2bf numerics identical to cvt_wo. out = Zb @ Wo^T + bo, fp32.
// ---------------------------------------------------------------------------
__global__ __launch_bounds__(256, 2)
void out_gemm(const unsigned short* __restrict__ A,
              const float* __restrict__ Wo, const float* __restrict__ bo,
              float* __restrict__ Out)
{
    __shared__ unsigned short Ash[128 * 32];
    __shared__ unsigned short Bsh[128 * 32];

    const int t = threadIdx.x;
    const int lane = t & 63, w = t >> 6;          // 4 waves
    const int lcol = lane & 15, quad = lane >> 4;
    const int rowBase = blockIdx.x * 128;         // token panel (32)
    const int colBase = blockIdx.y * 128;         // feature panel (8)
    const int wr = (w >> 1) * 64, wc = (w & 1) * 64;

    f32x4 acc[4][4];
    #pragma unroll
    for (int i = 0; i < 4; ++i)
        #pragma unroll
        for (int j = 0; j < 4; ++j) acc[i][j] = (f32x4){0.f,0.f,0.f,0.f};

    for (int k0 = 0; k0 < DM; k0 += 32) {
        __syncthreads();
        #pragma unroll
        for (int p = 0; p < 2; ++p) {
            int ci = p * 256 + t;
            glds16(&A[(size_t)(rowBase + (ci >> 2)) * DM + k0 + (ci & 3) * 8], &Ash[ci * 8]);
        }
        // B: Wo fp32 -> bf16 in-staging (chunk c: row=c>>2, col=(c&3)*8)
        #pragma unroll
        for (int p = 0; p < 2; ++p) {
            int c = p * 256 + t;
            int row = c >> 2, col = (c & 3) * 8;
            const float* ws_ = &Wo[(size_t)(colBase + row) * DM + k0 + col];
            float4 fa = *(const float4*)&ws_[0];
            float4 fb = *(const float4*)&ws_[4];
            uint4 wv;
            wv.x = pack2bf(fa.x, fa.y);
            wv.y = pack2bf(fa.z, fa.w);
            wv.z = pack2bf(fb.x, fb.y);
            wv.w = pack2bf(fb.z, fb.w);
            *(uint4*)&Bsh[row * 32 + col] = wv;
        }
        __syncthreads();
        bf16x8 af[4], bfr[4];
        #pragma unroll
        for (int i = 0; i < 4; ++i) af[i]  = *(const bf16x8*)&Ash[(wr + i*16 + lcol)*32 + quad*8];
        #pragma unroll
        for (int j = 0; j < 4; ++j) bfr[j] = *(const bf16x8*)&Bsh[(wc + j*16 + lcol)*32 + quad*8];
        #pragma unroll
        for (int i = 0; i < 4; ++i)
            #pragma unroll
            for (int j = 0; j < 4; ++j)
                acc[i][j] = __builtin_amdgcn_mfma_f32_16x16x32_bf16(af[i], bfr[j], acc[i][j], 0, 0, 0);
    }

    float bb[4];
    #pragma unroll
    for (int j = 0; j < 4; ++j) bb[j] = bo[colBase + wc + j*16 + lcol];

    #pragma unroll
    for (int i = 0; i < 4; ++i)
        #pragma unroll
        for (int j = 0; j < 4; ++j)
            #pragma unroll
            for (int r = 0; r < 4; ++r) {
                int row = rowBase + wr + i*16 + quad*4 + r;
                int col = colBase + wc + j*16 + lcol;
                Out[(size_t)row * DM + col] = acc[i][j][r] + bb[j];
            }
}

// ---------------------------------------------------------------------------
extern "C" void kernel_launch(void* const* d_in, const int* in_sizes, int n_in,
                              void* d_out, int out_size, void* d_ws, size_t ws_size,
                              hipStream_t stream) {
    const float* X  = (const float*)d_in[0];
    const float* Wq = (const float*)d_in[1];
    const float* Wk = (const float*)d_in[2];
    const float* Wv = (const float*)d_in[3];
    const float* Wo = (const float*)d_in[4];
    const float* bo = (const float*)d_in[5];
    float* out = (float*)d_out;

    // ws (32 MB): [Xb/Zb 8MB][Qw 8MB][Kw 8MB][Vtw 8MB]
    unsigned short* Xb  = (unsigned short*)d_ws;
    unsigned short* Qw  = Xb + (size_t)4096 * 1024;
    unsigned short* Kw  = Qw + (size_t)4096 * 1024;
    unsigned short* Vtw = Kw + (size_t)4096 * 1024;
    unsigned short* Zb  = Xb;                      // Xb dead after qkv_gemm
    // bf16 qkv-weights staged in d_out (6 MB of 16 MB); consumed by qkv_gemm,
    // which completes before out_gemm overwrites d_out (stream-ordered).
    unsigned short* Wb  = (unsigned short*)d_out;

    cvt_all<<<dim3(7168), 256, 0, stream>>>(X, Wq, Wk, Wv, Xb, Wb);
    qkv_gemm<<<dim3(32, 8, 3), 256, 0, stream>>>(Xb, Wb, Wb + (size_t)1048576,
                                                 Wb + (size_t)2097152, Qw, Kw, Vtw);
    attn_kernel<<<dim3(32, 16), 512, 0, stream>>>(Qw, Kw, Vtw, Zb);
    out_gemm<<<dim3(32, 8), 256, 0, stream>>>(Zb, Wo, bo, out);
}

// Round 11
// 183.046 us; speedup vs baseline: 1.0208x; 1.0208x over previous
//
#include <hip/hip_runtime.h>
#include <stdint.h>

typedef __bf16 bf16x8 __attribute__((ext_vector_type(8)));
typedef float  f32x4  __attribute__((ext_vector_type(4)));
typedef unsigned int u32x4 __attribute__((ext_vector_type(4)));

#define S_   2048
#define DM   1024
// 0.125 (=1/sqrt(64)) * log2(e), folded into Q projection epilogue so the
// attention softmax is a bare exp2 with no per-element scaling.
#define QSCALE 0.18033688011112042f

__device__ __forceinline__ unsigned short f2b(float f) {
    uint32_t u = __builtin_bit_cast(uint32_t, f);
    u += 0x7fffu + ((u >> 16) & 1u);
    return (unsigned short)(u >> 16);
}

// round-half-up bf16 pair pack: 2 adds + 1 v_perm
__device__ __forceinline__ uint32_t pack2bf(float a, float b) {
    uint32_t ua = __builtin_bit_cast(uint32_t, a) + 0x8000u;
    uint32_t ub = __builtin_bit_cast(uint32_t, b) + 0x8000u;
    return __builtin_amdgcn_perm(ub, ua, 0x07060302);
}

__device__ __forceinline__ void glds16(const void* g, void* l) {
    __builtin_amdgcn_global_load_lds(
        (const __attribute__((address_space(1))) void*)g,
        (__attribute__((address_space(3))) void*)l, 16, 0, 0);
}

// ---------------------------------------------------------------------------
// fp32 -> bf16 for X (4M elems -> Xb in ws) and Wq/Wk/Wv (3x1M -> Wb in d_out
// scratch; consumed by qkv_gemm, which finishes before out_gemm writes d_out).
// ---------------------------------------------------------------------------
__global__ void cvt_all(const float* __restrict__ X,
                        const float* __restrict__ Wq, const float* __restrict__ Wk,
                        const float* __restrict__ Wv,
                        unsigned short* __restrict__ Xb, unsigned short* __restrict__ Wb)
{
    size_t i = ((size_t)blockIdx.x * 256 + threadIdx.x) * 4;
    const float* src;
    unsigned short* dst;
    size_t off;
    if (i < (size_t)4194304) { src = X; dst = Xb; off = i; }
    else {
        size_t j = i - 4194304;
        int sel = (int)(j >> 20);
        off = j & 1048575;
        src = (sel == 0) ? Wq : (sel == 1) ? Wk : Wv;
        dst = Wb + (size_t)sel * 1048576;
    }
    float4 v = *(const float4*)&src[off];
    uint2 o;
    o.x = pack2bf(v.x, v.y);
    o.y = pack2bf(v.z, v.w);
    *(uint2*)&dst[off] = o;
}

// ---------------------------------------------------------------------------
// Fused QKV projection, m97 structure: both operands bf16 via global_load_lds.
// z=0: Q[tok][feat] (scaled by QSCALE), z=1: K[tok][feat], z=2: Vt[feat][tok].
// Grid (32,8,3); the 32-range (token panels for z!=2) rides blockIdx.x, so
// XCD = x&7 and same-XCD blocks share the X row-panel in that XCD's L2.
// ---------------------------------------------------------------------------
__global__ __launch_bounds__(256, 2)
void qkv_gemm(const unsigned short* __restrict__ Xb,
              const unsigned short* __restrict__ Wqb,
              const unsigned short* __restrict__ Wkb,
              const unsigned short* __restrict__ Wvb,
              unsigned short* __restrict__ Qo, unsigned short* __restrict__ Ko,
              unsigned short* __restrict__ Vto)
{
    __shared__ unsigned short Ash[128 * 32];
    __shared__ unsigned short Bsh[128 * 32];

    const int t = threadIdx.x;
    const int lane = t & 63, w = t >> 6;
    const int lcol = lane & 15, quad = lane >> 4;
    const int z = blockIdx.z;
    // x spans 32 (token panels), y spans 8 (feature panels); roles swap at z=2
    const int rowBase = ((z == 2) ? blockIdx.y : blockIdx.x) * 128;
    const int colBase = ((z == 2) ? blockIdx.x : blockIdx.y) * 128;
    const unsigned short* aPtr = (z == 2) ? Wvb : Xb;
    const unsigned short* bPtr = (z == 0) ? Wqb : (z == 1) ? Wkb : Xb;
    const int wr = (w >> 1) * 64, wc = (w & 1) * 64;

    f32x4 acc[4][4];
    #pragma unroll
    for (int i = 0; i < 4; ++i)
        #pragma unroll
        for (int j = 0; j < 4; ++j) acc[i][j] = (f32x4){0.f,0.f,0.f,0.f};

    for (int k0 = 0; k0 < DM; k0 += 32) {
        __syncthreads();
        #pragma unroll
        for (int p = 0; p < 2; ++p) {
            int ci = p * 256 + t;
            glds16(&aPtr[(size_t)(rowBase + (ci >> 2)) * DM + k0 + (ci & 3) * 8], &Ash[ci * 8]);
        }
        #pragma unroll
        for (int p = 0; p < 2; ++p) {
            int ci = p * 256 + t;
            glds16(&bPtr[(size_t)(colBase + (ci >> 2)) * DM + k0 + (ci & 3) * 8], &Bsh[ci * 8]);
        }
        __syncthreads();
        bf16x8 af[4], bfr[4];
        #pragma unroll
        for (int i = 0; i < 4; ++i) af[i]  = *(const bf16x8*)&Ash[(wr + i*16 + lcol)*32 + quad*8];
        #pragma unroll
        for (int i = 0; i < 4; ++i) bfr[i] = *(const bf16x8*)&Bsh[(wc + i*16 + lcol)*32 + quad*8];
        #pragma unroll
        for (int i = 0; i < 4; ++i)
            #pragma unroll
            for (int j = 0; j < 4; ++j)
                acc[i][j] = __builtin_amdgcn_mfma_f32_16x16x32_bf16(af[i], bfr[j], acc[i][j], 0, 0, 0);
    }

    unsigned short* Cm = (z == 0) ? Qo : (z == 1) ? Ko : Vto;
    const int ld = (z == 2) ? (S_ * 2) : DM;
    const float sc = (z == 0) ? QSCALE : 1.0f;
    #pragma unroll
    for (int i = 0; i < 4; ++i)
        #pragma unroll
        for (int j = 0; j < 4; ++j)
            #pragma unroll
            for (int r = 0; r < 4; ++r) {
                int row = rowBase + wr + i*16 + quad*4 + r;
                int col = colBase + wc + j*16 + lcol;
                Cm[(size_t)row * ld + col] = f2b(acc[i][j][r] * sc);
            }
}

// ---------------------------------------------------------------------------
// Flash attention, causal, S^T form, fixed softmax shift. 512 thr / 8 waves.
// Exact R2-measured kernel (43.5-45.0 us). Model (validated R2/R3/R6): time =
// (chunk-instances per CU = 34) x ~3.2k cyc, distribution-invariant.
//   * waves = 4 q-groups(32 rows) x 2 k-halves(32): each K/V ds_read_b128
//     fragment feeds TWO 16-q MFMAs. One-time cross-wave o/l reduction at end.
//   * Ps LDS roundtrip eliminated: P -> PV-A-fragment via __shfl_xor(16) +
//     select; k-slot permutation sigma=[0,2,1,3] folded into V read offset.
// Causal bounds wave-uniform: k16 idx Kb = c*4 + kh*2 + nk, q16 idx
// Qb = tile*8 + wq*2 + qi, live iff Kb <= Qb, diagonal masked via mk[].
// Grid (32,16): bh = blockIdx.x pins bh to XCD; y<8 ? 15-y : y-8 keeps the
// complementary tile pairing.
// ---------------------------------------------------------------------------
__global__ __launch_bounds__(512, 4)
void attn_kernel(const unsigned short* __restrict__ Q,
                 const unsigned short* __restrict__ K,
                 const unsigned short* __restrict__ Vt,
                 unsigned short* __restrict__ Z)
{
    // [Kbuf0 | Kbuf1 | Vbuf0 | Vbuf1], each 64 rows x 72 shorts (16B row pad).
    // After the main loop the same 36,864B are reused as the f32 reduction
    // buffer (4 q-groups x 64 lanes x 36 f32, stride 144B -> 16B aligned).
    __shared__ __align__(16) unsigned short SH[18432];

    const int t = threadIdx.x;
    const int lane = t & 63, w = t >> 6;          // 8 waves
    const int lcol = lane & 15, quad = lane >> 4;
    const int kh = w & 1, wq = w >> 1;            // k-half (32), q-group (32)

    const int bh = blockIdx.x;                    // XCD = bh & 7
    const int b = bh >> 4, h = bh & 15;
    const int y = blockIdx.y;
    const int tile = (y < 8) ? (15 - y) : (y - 8);
    const int q0 = tile * 128;
    const int nchunk = 2 * tile + 2;              // k-chunks of 64

    const unsigned short* Qg = Q + (size_t)(b * S_ + q0) * DM + h * 64;
    const unsigned short* Kg = K + (size_t)(b * S_) * DM + h * 64;
    const unsigned short* Vg = Vt + (size_t)(h * 64) * (S_ * 2) + b * S_;

    // Q fragments: 2 q-subgroups of 16 x 2 hd-halves
    bf16x8 qf[2][2];
    #pragma unroll
    for (int qi = 0; qi < 2; ++qi)
        #pragma unroll
        for (int kd = 0; kd < 2; ++kd)
            qf[qi][kd] = *(const bf16x8*)&Qg[(size_t)(wq*32 + qi*16 + lcol) * DM + kd*32 + quad*8];

    // mask pattern inside the diagonal 16x16 block (S^T form: mask k > q)
    bool mk[4];
    #pragma unroll
    for (int r = 0; r < 4; ++r) mk[r] = (quad*4 + r) > lcol;

    float lp[2] = {0.f, 0.f};
    f32x4 o[2][4];
    #pragma unroll
    for (int qi = 0; qi < 2; ++qi)
        #pragma unroll
        for (int nd = 0; nd < 4; ++nd) o[qi][nd] = (f32x4){0.f,0.f,0.f,0.f};

    // staging: 64 rows x 8 16B-chunks per tile; one K + one V load per thread
    const int sr = t >> 3, sch = t & 7;

    // prologue: stage chunk 0 into buffer 0
    {
        uint4 k0 = *(const uint4*)&Kg[(size_t)sr * DM + sch * 8];
        uint4 v0 = *(const uint4*)&Vg[(size_t)sr * (S_ * 2) + sch * 8];
        *(uint4*)&SH[sr * 72 + sch * 8] = k0;
        *(uint4*)&SH[9216 + sr * 72 + sch * 8] = v0;
    }
    __syncthreads();

    const int Qb0 = tile * 8 + wq * 2;                  // q16 idx of qi=0
    const int gq = ((quad & 1) << 1) | (quad >> 1);     // sigma = [0,2,1,3]
    const bool qodd = (quad & 1) != 0;

    for (int c = 0; c < nchunk; ++c) {
        const int cur = c & 1;
        const bool pf = (c + 1 < nchunk);
        uint4 kn, vn;
        if (pf) {                                 // issue loads for chunk c+1
            const int kc1 = (c + 1) * 64;
            kn = *(const uint4*)&Kg[(size_t)(kc1 + sr) * DM + sch * 8];
            vn = *(const uint4*)&Vg[(size_t)sr * (S_ * 2) + kc1 + sch * 8];
        }
        const unsigned short* Kc = &SH[cur * 4608];
        const unsigned short* Vc = &SH[9216 + cur * 4608];

        const int Kb0 = c * 4 + kh * 2;           // k16 idx of nk=0
        if (Kb0 <= Qb0 + 1) {                     // at least (nk=0,qi=1) live
            uint32_t pw[2][2][2];                 // [qi][nk][word], bf16 pairs
            #pragma unroll
            for (int nk = 0; nk < 2; ++nk) {
                const int Kb = Kb0 + nk;
                if (Kb <= Qb0 + 1) {
                    bf16x8 ak0 = *(const bf16x8*)&Kc[(kh*32 + nk*16 + lcol)*72 + quad*8];
                    bf16x8 ak1 = *(const bf16x8*)&Kc[(kh*32 + nk*16 + lcol)*72 + 32 + quad*8];
                    #pragma unroll
                    for (int qi = 0; qi < 2; ++qi) {
                        if (Kb <= Qb0 + qi) {
                            f32x4 s = (f32x4){0.f,0.f,0.f,0.f};
                            s = __builtin_amdgcn_mfma_f32_16x16x32_bf16(ak0, qf[qi][0], s, 0, 0, 0);
                            s = __builtin_amdgcn_mfma_f32_16x16x32_bf16(ak1, qf[qi][1], s, 0, 0, 0);
                            float p0 = __builtin_amdgcn_exp2f(s[0]);
                            float p1 = __builtin_amdgcn_exp2f(s[1]);
                            float p2 = __builtin_amdgcn_exp2f(s[2]);
                            float p3 = __builtin_amdgcn_exp2f(s[3]);
                            if (Kb == Qb0 + qi) { // diagonal block, uniform
                                p0 = mk[0] ? 0.f : p0;
                                p1 = mk[1] ? 0.f : p1;
                                p2 = mk[2] ? 0.f : p2;
                                p3 = mk[3] ? 0.f : p3;
                            }
                            lp[qi] += (p0 + p1) + (p2 + p3);
                            pw[qi][nk][0] = pack2bf(p0, p1);
                            pw[qi][nk][1] = pack2bf(p2, p3);
                        } else {
                            pw[qi][nk][0] = 0u;
                            pw[qi][nk][1] = 0u;
                        }
                    }
                } else {
                    #pragma unroll
                    for (int qi = 0; qi < 2; ++qi) {
                        pw[qi][nk][0] = 0u;
                        pw[qi][nk][1] = 0u;
                    }
                }
            }

            // register->A-fragment transform via shfl_xor(16) + select.
            // Source: lane (quad,q) word layout  a0={4q,4q+1} a1={4q+2,4q+3}
            //         b0={16+4q,16+4q+1} b1={16+4q+2,16+4q+3}
            // Dest quad d holds k-group sigma(d)*8..+7 ascending, sigma=[0,2,1,3];
            // V reads apply the same sigma via gq.
            bf16x8 ap[2];
            #pragma unroll
            for (int qi = 0; qi < 2; ++qi) {
                uint32_t a0 = pw[qi][0][0], a1 = pw[qi][0][1];
                uint32_t b0 = pw[qi][1][0], b1 = pw[qi][1][1];
                uint32_t xa0 = (uint32_t)__shfl_xor((int)a0, 16);
                uint32_t xa1 = (uint32_t)__shfl_xor((int)a1, 16);
                uint32_t xb0 = (uint32_t)__shfl_xor((int)b0, 16);
                uint32_t xb1 = (uint32_t)__shfl_xor((int)b1, 16);
                u32x4 apw;
                apw[0] = qodd ? xb0 : a0;
                apw[1] = qodd ? xb1 : a1;
                apw[2] = qodd ? b0 : xa0;
                apw[3] = qodd ? b1 : xa1;
                ap[qi] = __builtin_bit_cast(bf16x8, apw);
            }

            #pragma unroll
            for (int nd = 0; nd < 4; ++nd) {
                bf16x8 bv = *(const bf16x8*)&Vc[(nd*16 + lcol)*72 + kh*32 + gq*8];
                #pragma unroll
                for (int qi = 0; qi < 2; ++qi)
                    o[qi][nd] = __builtin_amdgcn_mfma_f32_16x16x32_bf16(ap[qi], bv, o[qi][nd], 0, 0, 0);
            }
        }

        if (pf) {                                 // write chunk c+1 into buf^1
            *(uint4*)&SH[(cur ^ 1) * 4608 + sr * 72 + sch * 8] = kn;
            *(uint4*)&SH[9216 + (cur ^ 1) * 4608 + sr * 72 + sch * 8] = vn;
        }
        __syncthreads();   // readers of buf^1 (iter c-1) done before its write
                           // is visible-required; writers done before iter c+1
    }

    // ---- combine k-halves: partner waves (wq,kh=1) -> (wq,kh=0) via LDS ----
    #pragma unroll
    for (int qi = 0; qi < 2; ++qi) {
        lp[qi] += __shfl_xor(lp[qi], 16);
        lp[qi] += __shfl_xor(lp[qi], 32);
    }
    float* red = (float*)SH;
    float* my = red + (wq * 64 + lane) * 36;      // 144B stride: 16B aligned
    if (kh == 1) {
        #pragma unroll
        for (int qi = 0; qi < 2; ++qi)
            #pragma unroll
            for (int nd = 0; nd < 4; ++nd)
                *(f32x4*)&my[qi*16 + nd*4] = o[qi][nd];
        my[32] = lp[0];
        my[33] = lp[1];
    }
    __syncthreads();
    if (kh == 0) {
        #pragma unroll
        for (int qi = 0; qi < 2; ++qi)
            #pragma unroll
            for (int nd = 0; nd < 4; ++nd)
                o[qi][nd] += *(const f32x4*)&my[qi*16 + nd*4];
        float linv[2];
        linv[0] = 1.0f / (lp[0] + my[32]);
        linv[1] = 1.0f / (lp[1] + my[33]);
        #pragma unroll
        for (int qi = 0; qi < 2; ++qi)
            #pragma unroll
            for (int r = 0; r < 4; ++r) {
                float lr = __shfl(linv[qi], quad*4 + r);
                unsigned short* Zr = Z + (size_t)(b*S_ + q0 + wq*32 + qi*16 + quad*4 + r) * DM + h*64;
                #pragma unroll
                for (int nd = 0; nd < 4; ++nd)
                    Zr[nd*16 + lcol] = f2b(o[qi][nd][r] * lr);
            }
    }
}

// ---------------------------------------------------------------------------
// Output projection, R17: fused Wo fp32->bf16 staging with LATENCY FIXED.
// R10's regression (+7us) was 4 waves/CU + zero prefetch: every k-step ate
// raw L2 latency. Now: 512 thr / 8 waves, tile 128x128 (wave 32x64), and the
// attn-proven dbuf issue-early/write-late schedule: at step k, issue A glds16
// (k+1 -> buf^1) + B fp32 loads (k+1 -> regs), compute k's 8 MFMAs, then
// pack+ds_write B, one barrier. Load latency hides under MFMA. Per thread per
// step: 1 glds16 + 2 dwordx4 + 2 pack + 1 ds_write_b128, conflict-free.
// Grid (32,8) = 256 blocks (1/CU, 8 waves). out = Zb @ Wo^T + bo, fp32.
// ---------------------------------------------------------------------------
__global__ __launch_bounds__(512, 2)
void out_gemm(const unsigned short* __restrict__ A,
              const float* __restrict__ Wo, const float* __restrict__ bo,
              float* __restrict__ Out)
{
    __shared__ unsigned short Ash[2][128 * 32];
    __shared__ unsigned short Bsh[2][128 * 32];

    const int t = threadIdx.x;
    const int lane = t & 63, w = t >> 6;          // 8 waves
    const int lcol = lane & 15, quad = lane >> 4;
    const int rowBase = blockIdx.x * 128;         // token panel (32)
    const int colBase = blockIdx.y * 128;         // feature panel (8)
    const int wr = (w >> 1) * 32, wc = (w & 1) * 64;   // 4x2 wave grid

    // staging maps (512 thr, 128x32 tiles): row = t>>2, col8 = (t&3)*8
    const int srow = t >> 2, scol = (t & 3) * 8;

    f32x4 acc[2][4];
    #pragma unroll
    for (int i = 0; i < 2; ++i)
        #pragma unroll
        for (int j = 0; j < 4; ++j) acc[i][j] = (f32x4){0.f,0.f,0.f,0.f};

    // prologue: stage k-step 0 into buffer 0
    {
        glds16(&A[(size_t)(rowBase + srow) * DM + scol], &Ash[0][t * 8]);
        const float* ws_ = &Wo[(size_t)(colBase + srow) * DM + scol];
        float4 fa = *(const float4*)&ws_[0];
        float4 fb = *(const float4*)&ws_[4];
        uint4 wv;
        wv.x = pack2bf(fa.x, fa.y);
        wv.y = pack2bf(fa.z, fa.w);
        wv.z = pack2bf(fb.x, fb.y);
        wv.w = pack2bf(fb.z, fb.w);
        *(uint4*)&Bsh[0][t * 8] = wv;
    }
    __syncthreads();

    for (int ks = 0; ks < 32; ++ks) {
        const int cur = ks & 1;
        const bool pf = (ks + 1 < 32);
        float4 fa, fb;
        if (pf) {                                 // issue k+1 loads
            const int k1 = (ks + 1) * 32;
            glds16(&A[(size_t)(rowBase + srow) * DM + k1 + scol], &Ash[cur ^ 1][t * 8]);
            const float* ws_ = &Wo[(size_t)(colBase + srow) * DM + k1 + scol];
            fa = *(const float4*)&ws_[0];
            fb = *(const float4*)&ws_[4];
        }

        bf16x8 af[2], bfr[4];
        #pragma unroll
        for (int i = 0; i < 2; ++i) af[i]  = *(const bf16x8*)&Ash[cur][(wr + i*16 + lcol)*32 + quad*8];
        #pragma unroll
        for (int j = 0; j < 4; ++j) bfr[j] = *(const bf16x8*)&Bsh[cur][(wc + j*16 + lcol)*32 + quad*8];
        #pragma unroll
        for (int i = 0; i < 2; ++i)
            #pragma unroll
            for (int j = 0; j < 4; ++j)
                acc[i][j] = __builtin_amdgcn_mfma_f32_16x16x32_bf16(af[i], bfr[j], acc[i][j], 0, 0, 0);

        if (pf) {                                 // write-late B(k+1)
            uint4 wv;
            wv.x = pack2bf(fa.x, fa.y);
            wv.y = pack2bf(fa.z, fa.w);
            wv.z = pack2bf(fb.x, fb.y);
            wv.w = pack2bf(fb.z, fb.w);
            *(uint4*)&Bsh[cur ^ 1][t * 8] = wv;
        }
        __syncthreads();   // drains glds16 (vmcnt) + ds_writes before flip
    }

    float bb[4];
    #pragma unroll
    for (int j = 0; j < 4; ++j) bb[j] = bo[colBase + wc + j*16 + lcol];

    #pragma unroll
    for (int i = 0; i < 2; ++i)
        #pragma unroll
        for (int j = 0; j < 4; ++j)
            #pragma unroll
            for (int r = 0; r < 4; ++r) {
                int row = rowBase + wr + i*16 + quad*4 + r;
                int col = colBase + wc + j*16 + lcol;
                Out[(size_t)row * DM + col] = acc[i][j][r] + bb[j];
            }
}

// ---------------------------------------------------------------------------
extern "C" void kernel_launch(void* const* d_in, const int* in_sizes, int n_in,
                              void* d_out, int out_size, void* d_ws, size_t ws_size,
                              hipStream_t stream) {
    const float* X  = (const float*)d_in[0];
    const float* Wq = (const float*)d_in[1];
    const float* Wk = (const float*)d_in[2];
    const float* Wv = (const float*)d_in[3];
    const float* Wo = (const float*)d_in[4];
    const float* bo = (const float*)d_in[5];
    float* out = (float*)d_out;

    // ws (32 MB): [Xb/Zb 8MB][Qw 8MB][Kw 8MB][Vtw 8MB]
    unsigned short* Xb  = (unsigned short*)d_ws;
    unsigned short* Qw  = Xb + (size_t)4096 * 1024;
    unsigned short* Kw  = Qw + (size_t)4096 * 1024;
    unsigned short* Vtw = Kw + (size_t)4096 * 1024;
    unsigned short* Zb  = Xb;                      // Xb dead after qkv_gemm
    // bf16 qkv-weights staged in d_out (6 MB of 16 MB); consumed by qkv_gemm,
    // which completes before out_gemm overwrites d_out (stream-ordered).
    unsigned short* Wb  = (unsigned short*)d_out;

    cvt_all<<<dim3(7168), 256, 0, stream>>>(X, Wq, Wk, Wv, Xb, Wb);
    qkv_gemm<<<dim3(32, 8, 3), 256, 0, stream>>>(Xb, Wb, Wb + (size_t)1048576,
                                                 Wb + (size_t)2097152, Qw, Kw, Vtw);
    attn_kernel<<<dim3(32, 16), 512, 0, stream>>>(Qw, Kw, Vtw, Zb);
    out_gemm<<<dim3(32, 8), 512, 0, stream>>>(Zb, Wo, bo, out);
}

// Round 12
// 176.020 us; speedup vs baseline: 1.0616x; 1.0399x over previous
//
#include <hip/hip_runtime.h>
#include <stdint.h>

typedef __bf16 bf16x8 __attribute__((ext_vector_type(8)));
typedef float  f32x4  __attribute__((ext_vector_type(4)));
typedef unsigned int u32x4 __attribute__((ext_vector_type(4)));

#define S_   2048
#define DM   1024
// 0.125 (=1/sqrt(64)) * log2(e), folded into Q projection epilogue so the
// attention softmax is a bare exp2 with no per-element scaling.
#define QSCALE 0.18033688011112042f

__device__ __forceinline__ unsigned short f2b(float f) {
    uint32_t u = __builtin_bit_cast(uint32_t, f);
    u += 0x7fffu + ((u >> 16) & 1u);
    return (unsigned short)(u >> 16);
}

// round-half-up bf16 pair pack: 2 adds + 1 v_perm
__device__ __forceinline__ uint32_t pack2bf(float a, float b) {
    uint32_t ua = __builtin_bit_cast(uint32_t, a) + 0x8000u;
    uint32_t ub = __builtin_bit_cast(uint32_t, b) + 0x8000u;
    return __builtin_amdgcn_perm(ub, ua, 0x07060302);
}

__device__ __forceinline__ void glds16(const void* g, void* l) {
    __builtin_amdgcn_global_load_lds(
        (const __attribute__((address_space(1))) void*)g,
        (__attribute__((address_space(3))) void*)l, 16, 0, 0);
}

// ---------------------------------------------------------------------------
// fp32 -> bf16 for X (4M elems -> Xb in ws) and Wq/Wk/Wv (3x1M -> Wb in d_out
// scratch; consumed by qkv_gemm, which finishes before out_gemm writes d_out).
// ---------------------------------------------------------------------------
__global__ void cvt_all(const float* __restrict__ X,
                        const float* __restrict__ Wq, const float* __restrict__ Wk,
                        const float* __restrict__ Wv,
                        unsigned short* __restrict__ Xb, unsigned short* __restrict__ Wb)
{
    size_t i = ((size_t)blockIdx.x * 256 + threadIdx.x) * 4;
    const float* src;
    unsigned short* dst;
    size_t off;
    if (i < (size_t)4194304) { src = X; dst = Xb; off = i; }
    else {
        size_t j = i - 4194304;
        int sel = (int)(j >> 20);
        off = j & 1048575;
        src = (sel == 0) ? Wq : (sel == 1) ? Wk : Wv;
        dst = Wb + (size_t)sel * 1048576;
    }
    float4 v = *(const float4*)&src[off];
    uint2 o;
    o.x = pack2bf(v.x, v.y);
    o.y = pack2bf(v.z, v.w);
    *(uint2*)&dst[off] = o;
}

// Wo fp32 -> bf16 (runs after attn; dest is the dead Qw region)
__global__ void cvt_wo(const float* __restrict__ Wo, unsigned short* __restrict__ Wob)
{
    size_t i = ((size_t)blockIdx.x * 256 + threadIdx.x) * 4;
    float4 v = *(const float4*)&Wo[i];
    uint2 o;
    o.x = pack2bf(v.x, v.y);
    o.y = pack2bf(v.z, v.w);
    *(uint2*)&Wob[i] = o;
}

// ---------------------------------------------------------------------------
// Fused QKV projection. R18: BK=64 -- k-steps 32 -> 16, halving the
// barrier-pair instances that dominate short-K GEMM cost. The 64-wide K-tile
// is stored as TWO independent [128][32] half-tiles (Ash[0]=k 0..31,
// Ash[1]=k 32..63): fragment ds_reads stay byte-identical to the proven m97
// pattern, and glds16 dests stay wave-linear per instruction (per-lane
// GLOBAL addresses are free; only the LDS dest must be linear). 8 glds16 /
// thread / step (same total staging instrs as BK=32), 32 MFMA/wave/step,
// ONE barrier pair. LDS 32KB -> 3 blocks/CU retained.
// z=0: Q[tok][feat] (scaled), z=1: K[tok][feat], z=2: Vt[feat][tok].
// Grid (32,8,3): token panels ride blockIdx.x -> XCD pinning for X reuse.
// ---------------------------------------------------------------------------
__global__ __launch_bounds__(256, 2)
void qkv_gemm(const unsigned short* __restrict__ Xb,
              const unsigned short* __restrict__ Wqb,
              const unsigned short* __restrict__ Wkb,
              const unsigned short* __restrict__ Wvb,
              unsigned short* __restrict__ Qo, unsigned short* __restrict__ Ko,
              unsigned short* __restrict__ Vto)
{
    __shared__ unsigned short Ash[2][128 * 32];
    __shared__ unsigned short Bsh[2][128 * 32];

    const int t = threadIdx.x;
    const int lane = t & 63, w = t >> 6;
    const int lcol = lane & 15, quad = lane >> 4;
    const int z = blockIdx.z;
    // x spans 32 (token panels), y spans 8 (feature panels); roles swap at z=2
    const int rowBase = ((z == 2) ? blockIdx.y : blockIdx.x) * 128;
    const int colBase = ((z == 2) ? blockIdx.x : blockIdx.y) * 128;
    const unsigned short* aPtr = (z == 2) ? Wvb : Xb;
    const unsigned short* bPtr = (z == 0) ? Wqb : (z == 1) ? Wkb : Xb;
    const int wr = (w >> 1) * 64, wc = (w & 1) * 64;

    f32x4 acc[4][4];
    #pragma unroll
    for (int i = 0; i < 4; ++i)
        #pragma unroll
        for (int j = 0; j < 4; ++j) acc[i][j] = (f32x4){0.f,0.f,0.f,0.f};

    for (int k0 = 0; k0 < DM; k0 += 64) {
        __syncthreads();
        #pragma unroll
        for (int kk = 0; kk < 2; ++kk)
            #pragma unroll
            for (int p = 0; p < 2; ++p) {
                int ci = p * 256 + t;
                glds16(&aPtr[(size_t)(rowBase + (ci >> 2)) * DM + k0 + kk*32 + (ci & 3) * 8],
                       &Ash[kk][ci * 8]);
            }
        #pragma unroll
        for (int kk = 0; kk < 2; ++kk)
            #pragma unroll
            for (int p = 0; p < 2; ++p) {
                int ci = p * 256 + t;
                glds16(&bPtr[(size_t)(colBase + (ci >> 2)) * DM + k0 + kk*32 + (ci & 3) * 8],
                       &Bsh[kk][ci * 8]);
            }
        __syncthreads();
        #pragma unroll
        for (int kk = 0; kk < 2; ++kk) {
            bf16x8 af[4], bfr[4];
            #pragma unroll
            for (int i = 0; i < 4; ++i) af[i]  = *(const bf16x8*)&Ash[kk][(wr + i*16 + lcol)*32 + quad*8];
            #pragma unroll
            for (int i = 0; i < 4; ++i) bfr[i] = *(const bf16x8*)&Bsh[kk][(wc + i*16 + lcol)*32 + quad*8];
            #pragma unroll
            for (int i = 0; i < 4; ++i)
                #pragma unroll
                for (int j = 0; j < 4; ++j)
                    acc[i][j] = __builtin_amdgcn_mfma_f32_16x16x32_bf16(af[i], bfr[j], acc[i][j], 0, 0, 0);
        }
    }

    unsigned short* Cm = (z == 0) ? Qo : (z == 1) ? Ko : Vto;
    const int ld = (z == 2) ? (S_ * 2) : DM;
    const float sc = (z == 0) ? QSCALE : 1.0f;
    #pragma unroll
    for (int i = 0; i < 4; ++i)
        #pragma unroll
        for (int j = 0; j < 4; ++j)
            #pragma unroll
            for (int r = 0; r < 4; ++r) {
                int row = rowBase + wr + i*16 + quad*4 + r;
                int col = colBase + wc + j*16 + lcol;
                Cm[(size_t)row * ld + col] = f2b(acc[i][j][r] * sc);
            }
}

// ---------------------------------------------------------------------------
// Flash attention, causal, S^T form, fixed softmax shift. 512 thr / 8 waves.
// Exact R2-measured kernel (43.5-45.0 us). Model (validated R2/R3/R6): time =
// (chunk-instances per CU = 34) x ~3.2k cyc, distribution-invariant.
//   * waves = 4 q-groups(32 rows) x 2 k-halves(32): each K/V ds_read_b128
//     fragment feeds TWO 16-q MFMAs. One-time cross-wave o/l reduction at end.
//   * Ps LDS roundtrip eliminated: P -> PV-A-fragment via __shfl_xor(16) +
//     select; k-slot permutation sigma=[0,2,1,3] folded into V read offset.
// Causal bounds wave-uniform: k16 idx Kb = c*4 + kh*2 + nk, q16 idx
// Qb = tile*8 + wq*2 + qi, live iff Kb <= Qb, diagonal masked via mk[].
// Grid (32,16): bh = blockIdx.x pins bh to XCD; y<8 ? 15-y : y-8 keeps the
// complementary tile pairing.
// ---------------------------------------------------------------------------
__global__ __launch_bounds__(512, 4)
void attn_kernel(const unsigned short* __restrict__ Q,
                 const unsigned short* __restrict__ K,
                 const unsigned short* __restrict__ Vt,
                 unsigned short* __restrict__ Z)
{
    // [Kbuf0 | Kbuf1 | Vbuf0 | Vbuf1], each 64 rows x 72 shorts (16B row pad).
    // After the main loop the same 36,864B are reused as the f32 reduction
    // buffer (4 q-groups x 64 lanes x 36 f32, stride 144B -> 16B aligned).
    __shared__ __align__(16) unsigned short SH[18432];

    const int t = threadIdx.x;
    const int lane = t & 63, w = t >> 6;          // 8 waves
    const int lcol = lane & 15, quad = lane >> 4;
    const int kh = w & 1, wq = w >> 1;            // k-half (32), q-group (32)

    const int bh = blockIdx.x;                    // XCD = bh & 7
    const int b = bh >> 4, h = bh & 15;
    const int y = blockIdx.y;
    const int tile = (y < 8) ? (15 - y) : (y - 8);
    const int q0 = tile * 128;
    const int nchunk = 2 * tile + 2;              // k-chunks of 64

    const unsigned short* Qg = Q + (size_t)(b * S_ + q0) * DM + h * 64;
    const unsigned short* Kg = K + (size_t)(b * S_) * DM + h * 64;
    const unsigned short* Vg = Vt + (size_t)(h * 64) * (S_ * 2) + b * S_;

    // Q fragments: 2 q-subgroups of 16 x 2 hd-halves
    bf16x8 qf[2][2];
    #pragma unroll
    for (int qi = 0; qi < 2; ++qi)
        #pragma unroll
        for (int kd = 0; kd < 2; ++kd)
            qf[qi][kd] = *(const bf16x8*)&Qg[(size_t)(wq*32 + qi*16 + lcol) * DM + kd*32 + quad*8];

    // mask pattern inside the diagonal 16x16 block (S^T form: mask k > q)
    bool mk[4];
    #pragma unroll
    for (int r = 0; r < 4; ++r) mk[r] = (quad*4 + r) > lcol;

    float lp[2] = {0.f, 0.f};
    f32x4 o[2][4];
    #pragma unroll
    for (int qi = 0; qi < 2; ++qi)
        #pragma unroll
        for (int nd = 0; nd < 4; ++nd) o[qi][nd] = (f32x4){0.f,0.f,0.f,0.f};

    // staging: 64 rows x 8 16B-chunks per tile; one K + one V load per thread
    const int sr = t >> 3, sch = t & 7;

    // prologue: stage chunk 0 into buffer 0
    {
        uint4 k0 = *(const uint4*)&Kg[(size_t)sr * DM + sch * 8];
        uint4 v0 = *(const uint4*)&Vg[(size_t)sr * (S_ * 2) + sch * 8];
        *(uint4*)&SH[sr * 72 + sch * 8] = k0;
        *(uint4*)&SH[9216 + sr * 72 + sch * 8] = v0;
    }
    __syncthreads();

    const int Qb0 = tile * 8 + wq * 2;                  // q16 idx of qi=0
    const int gq = ((quad & 1) << 1) | (quad >> 1);     // sigma = [0,2,1,3]
    const bool qodd = (quad & 1) != 0;

    for (int c = 0; c < nchunk; ++c) {
        const int cur = c & 1;
        const bool pf = (c + 1 < nchunk);
        uint4 kn, vn;
        if (pf) {                                 // issue loads for chunk c+1
            const int kc1 = (c + 1) * 64;
            kn = *(const uint4*)&Kg[(size_t)(kc1 + sr) * DM + sch * 8];
            vn = *(const uint4*)&Vg[(size_t)sr * (S_ * 2) + kc1 + sch * 8];
        }
        const unsigned short* Kc = &SH[cur * 4608];
        const unsigned short* Vc = &SH[9216 + cur * 4608];

        const int Kb0 = c * 4 + kh * 2;           // k16 idx of nk=0
        if (Kb0 <= Qb0 + 1) {                     // at least (nk=0,qi=1) live
            uint32_t pw[2][2][2];                 // [qi][nk][word], bf16 pairs
            #pragma unroll
            for (int nk = 0; nk < 2; ++nk) {
                const int Kb = Kb0 + nk;
                if (Kb <= Qb0 + 1) {
                    bf16x8 ak0 = *(const bf16x8*)&Kc[(kh*32 + nk*16 + lcol)*72 + quad*8];
                    bf16x8 ak1 = *(const bf16x8*)&Kc[(kh*32 + nk*16 + lcol)*72 + 32 + quad*8];
                    #pragma unroll
                    for (int qi = 0; qi < 2; ++qi) {
                        if (Kb <= Qb0 + qi) {
                            f32x4 s = (f32x4){0.f,0.f,0.f,0.f};
                            s = __builtin_amdgcn_mfma_f32_16x16x32_bf16(ak0, qf[qi][0], s, 0, 0, 0);
                            s = __builtin_amdgcn_mfma_f32_16x16x32_bf16(ak1, qf[qi][1], s, 0, 0, 0);
                            float p0 = __builtin_amdgcn_exp2f(s[0]);
                            float p1 = __builtin_amdgcn_exp2f(s[1]);
                            float p2 = __builtin_amdgcn_exp2f(s[2]);
                            float p3 = __builtin_amdgcn_exp2f(s[3]);
                            if (Kb == Qb0 + qi) { // diagonal block, uniform
                                p0 = mk[0] ? 0.f : p0;
                                p1 = mk[1] ? 0.f : p1;
                                p2 = mk[2] ? 0.f : p2;
                                p3 = mk[3] ? 0.f : p3;
                            }
                            lp[qi] += (p0 + p1) + (p2 + p3);
                            pw[qi][nk][0] = pack2bf(p0, p1);
                            pw[qi][nk][1] = pack2bf(p2, p3);
                        } else {
                            pw[qi][nk][0] = 0u;
                            pw[qi][nk][1] = 0u;
                        }
                    }
                } else {
                    #pragma unroll
                    for (int qi = 0; qi < 2; ++qi) {
                        pw[qi][nk][0] = 0u;
                        pw[qi][nk][1] = 0u;
                    }
                }
            }

            // register->A-fragment transform via shfl_xor(16) + select.
            // Source: lane (quad,q) word layout  a0={4q,4q+1} a1={4q+2,4q+3}
            //         b0={16+4q,16+4q+1} b1={16+4q+2,16+4q+3}
            // Dest quad d holds k-group sigma(d)*8..+7 ascending, sigma=[0,2,1,3];
            // V reads apply the same sigma via gq.
            bf16x8 ap[2];
            #pragma unroll
            for (int qi = 0; qi < 2; ++qi) {
                uint32_t a0 = pw[qi][0][0], a1 = pw[qi][0][1];
                uint32_t b0 = pw[qi][1][0], b1 = pw[qi][1][1];
                uint32_t xa0 = (uint32_t)__shfl_xor((int)a0, 16);
                uint32_t xa1 = (uint32_t)__shfl_xor((int)a1, 16);
                uint32_t xb0 = (uint32_t)__shfl_xor((int)b0, 16);
                uint32_t xb1 = (uint32_t)__shfl_xor((int)b1, 16);
                u32x4 apw;
                apw[0] = qodd ? xb0 : a0;
                apw[1] = qodd ? xb1 : a1;
                apw[2] = qodd ? b0 : xa0;
                apw[3] = qodd ? b1 : xa1;
                ap[qi] = __builtin_bit_cast(bf16x8, apw);
            }

            #pragma unroll
            for (int nd = 0; nd < 4; ++nd) {
                bf16x8 bv = *(const bf16x8*)&Vc[(nd*16 + lcol)*72 + kh*32 + gq*8];
                #pragma unroll
                for (int qi = 0; qi < 2; ++qi)
                    o[qi][nd] = __builtin_amdgcn_mfma_f32_16x16x32_bf16(ap[qi], bv, o[qi][nd], 0, 0, 0);
            }
        }

        if (pf) {                                 // write chunk c+1 into buf^1
            *(uint4*)&SH[(cur ^ 1) * 4608 + sr * 72 + sch * 8] = kn;
            *(uint4*)&SH[9216 + (cur ^ 1) * 4608 + sr * 72 + sch * 8] = vn;
        }
        __syncthreads();   // readers of buf^1 (iter c-1) done before its write
                           // is visible-required; writers done before iter c+1
    }

    // ---- combine k-halves: partner waves (wq,kh=1) -> (wq,kh=0) via LDS ----
    #pragma unroll
    for (int qi = 0; qi < 2; ++qi) {
        lp[qi] += __shfl_xor(lp[qi], 16);
        lp[qi] += __shfl_xor(lp[qi], 32);
    }
    float* red = (float*)SH;
    float* my = red + (wq * 64 + lane) * 36;      // 144B stride: 16B aligned
    if (kh == 1) {
        #pragma unroll
        for (int qi = 0; qi < 2; ++qi)
            #pragma unroll
            for (int nd = 0; nd < 4; ++nd)
                *(f32x4*)&my[qi*16 + nd*4] = o[qi][nd];
        my[32] = lp[0];
        my[33] = lp[1];
    }
    __syncthreads();
    if (kh == 0) {
        #pragma unroll
        for (int qi = 0; qi < 2; ++qi)
            #pragma unroll
            for (int nd = 0; nd < 4; ++nd)
                o[qi][nd] += *(const f32x4*)&my[qi*16 + nd*4];
        float linv[2];
        linv[0] = 1.0f / (lp[0] + my[32]);
        linv[1] = 1.0f / (lp[1] + my[33]);
        #pragma unroll
        for (int qi = 0; qi < 2; ++qi)
            #pragma unroll
            for (int r = 0; r < 4; ++r) {
                float lr = __shfl(linv[qi], quad*4 + r);
                unsigned short* Zr = Z + (size_t)(b*S_ + q0 + wq*32 + qi*16 + quad*4 + r) * DM + h*64;
                #pragma unroll
                for (int nd = 0; nd < 4; ++nd)
                    Zr[nd*16 + lcol] = f2b(o[qi][nd][r] * lr);
            }
    }
}

// ---------------------------------------------------------------------------
// Output projection, R18: tile 128x128, grid (32,8), 256 thr / 4 waves,
// BK=64 dual-half-tile structure (same as qkv): k-steps 32 -> 16, one
// barrier pair per step, proven [128][32] read pattern per half.
// B = Wob bf16 (from cvt_wo) via glds16. out = Zb @ Wob^T + bo, fp32.
// ---------------------------------------------------------------------------
__global__ __launch_bounds__(256, 2)
void out_gemm(const unsigned short* __restrict__ A,
              const unsigned short* __restrict__ Wob, const float* __restrict__ bo,
              float* __restrict__ Out)
{
    __shared__ unsigned short Ash[2][128 * 32];
    __shared__ unsigned short Bsh[2][128 * 32];

    const int t = threadIdx.x;
    const int lane = t & 63, w = t >> 6;          // 4 waves
    const int lcol = lane & 15, quad = lane >> 4;
    const int rowBase = blockIdx.x * 128;         // token panel (32)
    const int colBase = blockIdx.y * 128;         // feature panel (8)
    const int wr = (w >> 1) * 64, wc = (w & 1) * 64;

    f32x4 acc[4][4];
    #pragma unroll
    for (int i = 0; i < 4; ++i)
        #pragma unroll
        for (int j = 0; j < 4; ++j) acc[i][j] = (f32x4){0.f,0.f,0.f,0.f};

    for (int k0 = 0; k0 < DM; k0 += 64) {
        __syncthreads();
        #pragma unroll
        for (int kk = 0; kk < 2; ++kk)
            #pragma unroll
            for (int p = 0; p < 2; ++p) {
                int ci = p * 256 + t;
                glds16(&A[(size_t)(rowBase + (ci >> 2)) * DM + k0 + kk*32 + (ci & 3) * 8],
                       &Ash[kk][ci * 8]);
            }
        #pragma unroll
        for (int kk = 0; kk < 2; ++kk)
            #pragma unroll
            for (int p = 0; p < 2; ++p) {
                int ci = p * 256 + t;
                glds16(&Wob[(size_t)(colBase + (ci >> 2)) * DM + k0 + kk*32 + (ci & 3) * 8],
                       &Bsh[kk][ci * 8]);
            }
        __syncthreads();
        #pragma unroll
        for (int kk = 0; kk < 2; ++kk) {
            bf16x8 af[4], bfr[4];
            #pragma unroll
            for (int i = 0; i < 4; ++i) af[i]  = *(const bf16x8*)&Ash[kk][(wr + i*16 + lcol)*32 + quad*8];
            #pragma unroll
            for (int j = 0; j < 4; ++j) bfr[j] = *(const bf16x8*)&Bsh[kk][(wc + j*16 + lcol)*32 + quad*8];
            #pragma unroll
            for (int i = 0; i < 4; ++i)
                #pragma unroll
                for (int j = 0; j < 4; ++j)
                    acc[i][j] = __builtin_amdgcn_mfma_f32_16x16x32_bf16(af[i], bfr[j], acc[i][j], 0, 0, 0);
        }
    }

    float bb[4];
    #pragma unroll
    for (int j = 0; j < 4; ++j) bb[j] = bo[colBase + wc + j*16 + lcol];

    #pragma unroll
    for (int i = 0; i < 4; ++i)
        #pragma unroll
        for (int j = 0; j < 4; ++j)
            #pragma unroll
            for (int r = 0; r < 4; ++r) {
                int row = rowBase + wr + i*16 + quad*4 + r;
                int col = colBase + wc + j*16 + lcol;
                Out[(size_t)row * DM + col] = acc[i][j][r] + bb[j];
            }
}

// ---------------------------------------------------------------------------
extern "C" void kernel_launch(void* const* d_in, const int* in_sizes, int n_in,
                              void* d_out, int out_size, void* d_ws, size_t ws_size,
                              hipStream_t stream) {
    const float* X  = (const float*)d_in[0];
    const float* Wq = (const float*)d_in[1];
    const float* Wk = (const float*)d_in[2];
    const float* Wv = (const float*)d_in[3];
    const float* Wo = (const float*)d_in[4];
    const float* bo = (const float*)d_in[5];
    float* out = (float*)d_out;

    // ws (32 MB): [Xb/Zb 8MB][Qw/Wob 8MB][Kw 8MB][Vtw 8MB]
    unsigned short* Xb  = (unsigned short*)d_ws;
    unsigned short* Qw  = Xb + (size_t)4096 * 1024;
    unsigned short* Kw  = Qw + (size_t)4096 * 1024;
    unsigned short* Vtw = Kw + (size_t)4096 * 1024;
    unsigned short* Zb  = Xb;                      // Xb dead after qkv_gemm
    unsigned short* Wob = Qw;                      // Qw dead after attn_kernel
    // bf16 qkv-weights staged in d_out (6 MB of 16 MB); consumed by qkv_gemm,
    // which completes before out_gemm overwrites d_out (stream-ordered).
    unsigned short* Wb  = (unsigned short*)d_out;

    cvt_all<<<dim3(7168), 256, 0, stream>>>(X, Wq, Wk, Wv, Xb, Wb);
    qkv_gemm<<<dim3(32, 8, 3), 256, 0, stream>>>(Xb, Wb, Wb + (size_t)1048576,
                                                 Wb + (size_t)2097152, Qw, Kw, Vtw);
    attn_kernel<<<dim3(32, 16), 512, 0, stream>>>(Qw, Kw, Vtw, Zb);
    cvt_wo<<<dim3(1024), 256, 0, stream>>>(Wo, Wob);
    out_gemm<<<dim3(32, 8), 256, 0, stream>>>(Zb, Wob, bo, out);
}